// Round 5
// baseline (69.577 us; speedup 1.0000x reference)
//
#include <hip/hip_runtime.h>

#define EPS 1e-10f

// Inline-asm global load: result is pinned in registers the compiler must
// keep live; issue position is pinned by volatile ordering + sched_barrier.
#define GLOAD4(dst, addr) \
    asm volatile("global_load_dwordx4 %0, %1, off" : "=&v"(dst) : "v"(addr) : "memory")

// Stage 1: software-pipelined (depth 1, 5 loads in flight) fused dual-loss.
// Requires n4 == gridDim.x * 256 * NITER (host guarantees).
template<int NITER, int SHIFT>
__global__ __launch_bounds__(256) void loss_asm_kernel(
    const float4* __restrict__ in4,
    const float4* __restrict__ tg4,
    const float*  __restrict__ weight,
    const float4* __restrict__ st4,
    const float4* __restrict__ tp4,
    const float4* __restrict__ so4,
    float2* __restrict__ part,
    int stride4)                    // gridDim.x * 256
{
    const int i0 = blockIdx.x * 256 + threadIdx.x;

    // Load all per-iter row weights up front and DRAIN, so the compiler has
    // no vmem ops of its own inside the asm-pipelined region (its vmcnt
    // bookkeeping would otherwise be wrong/conservative).
    float w2[NITER];
#pragma unroll
    for (int k = 0; k < NITER; ++k) {
        float w = weight[(i0 + k * stride4) >> SHIFT];
        w2[k] = w * w;
    }
    asm volatile("s_waitcnt vmcnt(0) lgkmcnt(0)" ::: "memory");
    __builtin_amdgcn_sched_barrier(0);

    const float4* a_in = in4 + i0;
    const float4* a_tg = tg4 + i0;
    const float4* a_st = st4 + i0;
    const float4* a_tp = tp4 + i0;
    const float4* a_so = so4 + i0;

    // prologue: issue batch 0
    float4 cx, ct, cs, cp, co;
    GLOAD4(cx, a_in);
    GLOAD4(ct, a_tg);
    GLOAD4(cs, a_st);
    GLOAD4(cp, a_tp);
    GLOAD4(co, a_so);
    __builtin_amdgcn_sched_barrier(0);

    float s_mse = 0.0f;
    float s_wcl = 0.0f;

#pragma unroll
    for (int k = 0; k < NITER; ++k) {
        float4 nx, nt, ns, nq, no;
        if (k + 1 < NITER) {
            // issue next batch BEFORE consuming current
            a_in += stride4; a_tg += stride4; a_st += stride4;
            a_tp += stride4; a_so += stride4;
            GLOAD4(nx, a_in);
            GLOAD4(nt, a_tg);
            GLOAD4(ns, a_st);
            GLOAD4(nq, a_tp);
            GLOAD4(no, a_so);
            __builtin_amdgcn_sched_barrier(0);
            // 10 outstanding; wait until the 5 older (current batch) land,
            // leaving the 5 new ones in flight under the compute below.
            asm volatile("s_waitcnt vmcnt(5)" ::: "memory");
        } else {
            asm volatile("s_waitcnt vmcnt(0)" ::: "memory");
        }
        // Fence: keep the compute below from hoisting above the waitcnt
        // (hipcc moves register-only ops past inline-asm waits otherwise).
        __builtin_amdgcn_sched_barrier(0);

        const float w2k = w2[k];
        float d0 = ct.x - cx.x, d1 = ct.y - cx.y;
        float d2 = ct.z - cx.z, d3 = ct.w - cx.w;
        s_mse += w2k * (d0 * d0);
        s_mse += w2k * (d1 * d1);
        s_mse += w2k * (d2 * d2);
        s_mse += w2k * (d3 * d3);

        float b0 = cs.x * __logf(cp.x + EPS) + (1.0f - cs.x) * __logf(1.0f - cp.x + EPS);
        float b1 = cs.y * __logf(cp.y + EPS) + (1.0f - cs.y) * __logf(1.0f - cp.y + EPS);
        float b2 = cs.z * __logf(cp.z + EPS) + (1.0f - cs.z) * __logf(1.0f - cp.z + EPS);
        float b3 = cs.w * __logf(cp.w + EPS) + (1.0f - cs.w) * __logf(1.0f - cp.w + EPS);
        s_wcl += fabsf(b0 * co.x);
        s_wcl += fabsf(b1 * co.y);
        s_wcl += fabsf(b2 * co.z);
        s_wcl += fabsf(b3 * co.w);

        if (k + 1 < NITER) {
            cx = nx; ct = nt; cs = ns; cp = nq; co = no;
        }
    }

    // wave (64-lane) shuffle reduction
    for (int off = 32; off > 0; off >>= 1) {
        s_mse += __shfl_down(s_mse, off, 64);
        s_wcl += __shfl_down(s_wcl, off, 64);
    }

    __shared__ float lds_mse[4];
    __shared__ float lds_wcl[4];
    int lane = threadIdx.x & 63;
    int wid  = threadIdx.x >> 6;
    if (lane == 0) {
        lds_mse[wid] = s_mse;
        lds_wcl[wid] = s_wcl;
    }
    __syncthreads();
    if (threadIdx.x == 0) {
        part[blockIdx.x] = make_float2(
            lds_mse[0] + lds_mse[1] + lds_mse[2] + lds_mse[3],
            lds_wcl[0] + lds_wcl[1] + lds_wcl[2] + lds_wcl[3]);
    }
}

// Stage 2: one block reduces nPart float2 partials, writes the 2 outputs.
__global__ __launch_bounds__(256) void loss_stage2_kernel(
    const float2* __restrict__ part,
    float* __restrict__ out,
    int nPart,
    float inv_count)
{
    float s_mse = 0.0f, s_wcl = 0.0f;
    for (int i = threadIdx.x; i < nPart; i += 256) {
        float2 p = part[i];
        s_mse += p.x;
        s_wcl += p.y;
    }
    for (int off = 32; off > 0; off >>= 1) {
        s_mse += __shfl_down(s_mse, off, 64);
        s_wcl += __shfl_down(s_wcl, off, 64);
    }
    __shared__ float lds_mse[4];
    __shared__ float lds_wcl[4];
    int lane = threadIdx.x & 63;
    int wid  = threadIdx.x >> 6;
    if (lane == 0) { lds_mse[wid] = s_mse; lds_wcl[wid] = s_wcl; }
    __syncthreads();
    if (threadIdx.x == 0) {
        out[0] = (lds_mse[0] + lds_mse[1] + lds_mse[2] + lds_mse[3]) * inv_count;
        out[1] = (lds_wcl[0] + lds_wcl[1] + lds_wcl[2] + lds_wcl[3]) * inv_count;
    }
}

// Generic fallback (arbitrary shapes).
__global__ __launch_bounds__(256) void loss_generic_kernel(
    const float* __restrict__ input,
    const float* __restrict__ target,
    const float* __restrict__ weight,
    const float* __restrict__ sub_target,
    const float* __restrict__ target_pre,
    const float* __restrict__ sub_obrT,
    float2* __restrict__ part,
    int total, int D)
{
    float s_mse = 0.0f, s_wcl = 0.0f;
    int idx = blockIdx.x * blockDim.x + threadIdx.x;
    int stride = gridDim.x * blockDim.x;
    for (int i = idx; i < total; i += stride) {
        float w = weight[i / D];
        float d = target[i] - input[i];
        s_mse += w * w * d * d;
        float st = sub_target[i], tp = target_pre[i];
        float b = st * __logf(tp + EPS) + (1.0f - st) * __logf(1.0f - tp + EPS);
        s_wcl += fabsf(b * sub_obrT[i]);
    }
    for (int off = 32; off > 0; off >>= 1) {
        s_mse += __shfl_down(s_mse, off, 64);
        s_wcl += __shfl_down(s_wcl, off, 64);
    }
    __shared__ float lds_mse[4];
    __shared__ float lds_wcl[4];
    int lane = threadIdx.x & 63;
    int wid  = threadIdx.x >> 6;
    if (lane == 0) { lds_mse[wid] = s_mse; lds_wcl[wid] = s_wcl; }
    __syncthreads();
    if (threadIdx.x == 0) {
        part[blockIdx.x] = make_float2(
            lds_mse[0] + lds_mse[1] + lds_mse[2] + lds_mse[3],
            lds_wcl[0] + lds_wcl[1] + lds_wcl[2] + lds_wcl[3]);
    }
}

extern "C" void kernel_launch(void* const* d_in, const int* in_sizes, int n_in,
                              void* d_out, int out_size, void* d_ws, size_t ws_size,
                              hipStream_t stream) {
    const float* input      = (const float*)d_in[0];
    const float* target     = (const float*)d_in[1];
    const float* weight     = (const float*)d_in[2];
    const float* sub_target = (const float*)d_in[3];
    const float* target_pre = (const float*)d_in[4];
    const float* sub_obrT   = (const float*)d_in[5];
    float* out = (float*)d_out;

    const int ND = in_sizes[0];      // N*D
    const int N  = in_sizes[2];      // weight length
    const int D  = ND / N;
    const int n4 = ND / 4;

    float2* part = (float2*)d_ws;

    constexpr int NITER = 8;
    const int chunk = 256 * NITER;            // float4 per block
    if (D == 2048 && n4 % chunk == 0) {
        const int grid = n4 / chunk;          // 2048 for 8192x2048
        loss_asm_kernel<NITER, 9><<<grid, 256, 0, stream>>>(
            (const float4*)input, (const float4*)target, weight,
            (const float4*)sub_target, (const float4*)target_pre,
            (const float4*)sub_obrT, part, grid * 256);
        loss_stage2_kernel<<<1, 256, 0, stream>>>(part, out, grid, 1.0f / (float)ND);
    } else {
        int grid = (ND + 255) / 256;
        if (grid > 2048) grid = 2048;
        if (grid < 1) grid = 1;
        loss_generic_kernel<<<grid, 256, 0, stream>>>(
            input, target, weight, sub_target, target_pre, sub_obrT, part, ND, D);
        loss_stage2_kernel<<<1, 256, 0, stream>>>(part, out, grid, 1.0f / (float)ND);
    }
}

// Round 6
// 62.033 us; speedup vs baseline: 1.1216x; 1.1216x over previous
//
#include <hip/hip_runtime.h>

#define EPS 1e-10f

// Stage 1: grid-stride fused dual-loss, static trip count.
// Requires n4 == gridDim.x * 256 * NITER (host guarantees).
// Each block writes one float2 partial {mse_sum, wcl_sum} to part[] --
// NO atomics (same-address f64 atomic bursts serialize across XCDs: -25us).
// NOTE (R1/R2/R4 post-mortems): source-level software pipelining, sched_barrier
// pinning, and inline-asm vmcnt pipelines were all neutral-to-negative here;
// the kernel streams at ~6.0 TB/s effective (~95% of m13's 6.29 TB/s device
// ceiling). Keep this simple form.
template<int NITER, int SHIFT>
__global__ __launch_bounds__(256) void loss_stage1_kernel(
    const float4* __restrict__ in4,
    const float4* __restrict__ tg4,
    const float*  __restrict__ weight,
    const float4* __restrict__ st4,
    const float4* __restrict__ tp4,
    const float4* __restrict__ so4,
    float2* __restrict__ part,
    int stride4)                    // gridDim.x * 256
{
    int i = blockIdx.x * 256 + threadIdx.x;

    float s_mse = 0.0f;
    float s_wcl = 0.0f;

#pragma unroll
    for (int k = 0; k < NITER; ++k, i += stride4) {
        float4 x  = in4[i];
        float4 t  = tg4[i];
        float4 st = st4[i];
        float4 tp = tp4[i];
        float4 so = so4[i];
        float  w  = weight[i >> SHIFT];

        const float w2 = w * w;
        float d0 = t.x - x.x, d1 = t.y - x.y;
        float d2 = t.z - x.z, d3 = t.w - x.w;
        s_mse += w2 * (d0 * d0);
        s_mse += w2 * (d1 * d1);
        s_mse += w2 * (d2 * d2);
        s_mse += w2 * (d3 * d3);

        float b0 = st.x * __logf(tp.x + EPS) + (1.0f - st.x) * __logf(1.0f - tp.x + EPS);
        float b1 = st.y * __logf(tp.y + EPS) + (1.0f - st.y) * __logf(1.0f - tp.y + EPS);
        float b2 = st.z * __logf(tp.z + EPS) + (1.0f - st.z) * __logf(1.0f - tp.z + EPS);
        float b3 = st.w * __logf(tp.w + EPS) + (1.0f - st.w) * __logf(1.0f - tp.w + EPS);
        s_wcl += fabsf(b0 * so.x);
        s_wcl += fabsf(b1 * so.y);
        s_wcl += fabsf(b2 * so.z);
        s_wcl += fabsf(b3 * so.w);
    }

    // wave (64-lane) shuffle reduction
    for (int off = 32; off > 0; off >>= 1) {
        s_mse += __shfl_down(s_mse, off, 64);
        s_wcl += __shfl_down(s_wcl, off, 64);
    }

    __shared__ float lds_mse[4];
    __shared__ float lds_wcl[4];
    int lane = threadIdx.x & 63;
    int wid  = threadIdx.x >> 6;
    if (lane == 0) {
        lds_mse[wid] = s_mse;
        lds_wcl[wid] = s_wcl;
    }
    __syncthreads();
    if (threadIdx.x == 0) {
        part[blockIdx.x] = make_float2(
            lds_mse[0] + lds_mse[1] + lds_mse[2] + lds_mse[3],
            lds_wcl[0] + lds_wcl[1] + lds_wcl[2] + lds_wcl[3]);
    }
}

// Stage 2: one block reduces nPart float2 partials, writes the 2 outputs.
__global__ __launch_bounds__(256) void loss_stage2_kernel(
    const float2* __restrict__ part,
    float* __restrict__ out,
    int nPart,
    float inv_count)
{
    float s_mse = 0.0f, s_wcl = 0.0f;
    for (int i = threadIdx.x; i < nPart; i += 256) {
        float2 p = part[i];
        s_mse += p.x;
        s_wcl += p.y;
    }
    for (int off = 32; off > 0; off >>= 1) {
        s_mse += __shfl_down(s_mse, off, 64);
        s_wcl += __shfl_down(s_wcl, off, 64);
    }
    __shared__ float lds_mse[4];
    __shared__ float lds_wcl[4];
    int lane = threadIdx.x & 63;
    int wid  = threadIdx.x >> 6;
    if (lane == 0) { lds_mse[wid] = s_mse; lds_wcl[wid] = s_wcl; }
    __syncthreads();
    if (threadIdx.x == 0) {
        out[0] = (lds_mse[0] + lds_mse[1] + lds_mse[2] + lds_mse[3]) * inv_count;
        out[1] = (lds_wcl[0] + lds_wcl[1] + lds_wcl[2] + lds_wcl[3]) * inv_count;
    }
}

// Generic fallback (arbitrary shapes): grid-stride, partials, then stage 2.
__global__ __launch_bounds__(256) void loss_generic_kernel(
    const float* __restrict__ input,
    const float* __restrict__ target,
    const float* __restrict__ weight,
    const float* __restrict__ sub_target,
    const float* __restrict__ target_pre,
    const float* __restrict__ sub_obrT,
    float2* __restrict__ part,
    int total, int D)
{
    float s_mse = 0.0f, s_wcl = 0.0f;
    int idx = blockIdx.x * blockDim.x + threadIdx.x;
    int stride = gridDim.x * blockDim.x;
    for (int i = idx; i < total; i += stride) {
        float w = weight[i / D];
        float d = target[i] - input[i];
        s_mse += w * w * d * d;
        float st = sub_target[i], tp = target_pre[i];
        float b = st * __logf(tp + EPS) + (1.0f - st) * __logf(1.0f - tp + EPS);
        s_wcl += fabsf(b * sub_obrT[i]);
    }
    for (int off = 32; off > 0; off >>= 1) {
        s_mse += __shfl_down(s_mse, off, 64);
        s_wcl += __shfl_down(s_wcl, off, 64);
    }
    __shared__ float lds_mse[4];
    __shared__ float lds_wcl[4];
    int lane = threadIdx.x & 63;
    int wid  = threadIdx.x >> 6;
    if (lane == 0) { lds_mse[wid] = s_mse; lds_wcl[wid] = s_wcl; }
    __syncthreads();
    if (threadIdx.x == 0) {
        part[blockIdx.x] = make_float2(
            lds_mse[0] + lds_mse[1] + lds_mse[2] + lds_mse[3],
            lds_wcl[0] + lds_wcl[1] + lds_wcl[2] + lds_wcl[3]);
    }
}

extern "C" void kernel_launch(void* const* d_in, const int* in_sizes, int n_in,
                              void* d_out, int out_size, void* d_ws, size_t ws_size,
                              hipStream_t stream) {
    const float* input      = (const float*)d_in[0];
    const float* target     = (const float*)d_in[1];
    const float* weight     = (const float*)d_in[2];
    const float* sub_target = (const float*)d_in[3];
    const float* target_pre = (const float*)d_in[4];
    const float* sub_obrT   = (const float*)d_in[5];
    float* out = (float*)d_out;

    const int ND = in_sizes[0];      // N*D
    const int N  = in_sizes[2];      // weight length
    const int D  = ND / N;
    const int n4 = ND / 4;

    float2* part = (float2*)d_ws;

    constexpr int NITER = 8;
    const int chunk = 256 * NITER;            // float4 per block
    if (D == 2048 && n4 % chunk == 0) {
        const int grid = n4 / chunk;          // 2048 for 8192x2048
        loss_stage1_kernel<NITER, 9><<<grid, 256, 0, stream>>>(
            (const float4*)input, (const float4*)target, weight,
            (const float4*)sub_target, (const float4*)target_pre,
            (const float4*)sub_obrT, part, grid * 256);
        loss_stage2_kernel<<<1, 256, 0, stream>>>(part, out, grid, 1.0f / (float)ND);
    } else {
        int grid = (ND + 255) / 256;
        if (grid > 2048) grid = 2048;
        if (grid < 1) grid = 1;
        loss_generic_kernel<<<grid, 256, 0, stream>>>(
            input, target, weight, sub_target, target_pre, sub_obrT, part, ND, D);
        loss_stage2_kernel<<<1, 256, 0, stream>>>(part, out, grid, 1.0f / (float)ND);
    }
}